// Round 11
// baseline (1521.910 us; speedup 1.0000x reference)
//
#include <hip/hip_runtime.h>

#define TT 40
#define NB 256
#define DD 2048
#define HISTL 28  // history rows kept in LDS; rows >= HISTL live in global ws

typedef __bf16 bf16x8 __attribute__((ext_vector_type(8)));
typedef float f32x4 __attribute__((ext_vector_type(4)));
typedef unsigned short u16;
typedef unsigned int u32;
typedef u16 u16x8 __attribute__((ext_vector_type(8)));
typedef u16 u16x4 __attribute__((ext_vector_type(4)));

__device__ __forceinline__ u16 f2bf(float f) {
  u32 u = __builtin_bit_cast(u32, f);
  return (u16)((u + 0x7fffu + ((u >> 16) & 1u)) >> 16);
}
__device__ __forceinline__ float bf2f(u16 h) {
  return __builtin_bit_cast(float, ((u32)h) << 16);
}
__device__ __forceinline__ bf16x8 asbf(u16x8 v) { return __builtin_bit_cast(bf16x8, v); }

__device__ __forceinline__ float sigm(float x) { return 1.0f / (1.0f + __expf(-x)); }
__device__ __forceinline__ float tanh_(float x) {
  float e = __expf(-2.0f * fabsf(x));
  float t = (1.0f - e) / (1.0f + e);
  return copysignf(t, x);
}

__device__ __forceinline__ f32x4 mfma16(bf16x8 a, bf16x8 b, f32x4 c) {
  return __builtin_amdgcn_mfma_f32_16x16x32_bf16(a, b, c, 0, 0, 0);
}

__device__ __forceinline__ int imin(int a, int b) { return a < b ? a : b; }

// wave-uniform lane broadcast via v_readlane (SALU path, no LDS traffic)
__device__ __forceinline__ float rdlane(float v, int l) {
  return __builtin_bit_cast(float, __builtin_amdgcn_readlane(__builtin_bit_cast(int, v), l));
}

// ---------------- weight prep: reorder W into A-fragment layout, bf16 ----------------
// A-frag for tile (kt, mt): lane l, elem j holds A[row = mt*16 + (l&15), k = kt*32 + (l>>4)*8 + j]
// row p is PERMUTED oc: oc = (p&3)*32 + ((p>>5)&3)*8 + ((p>>4)&1)*4 + ((p>>2)&3)
// K ordering: k = (ky*KK + kx)*64 + ic
__global__ void prep_weights(const float* __restrict__ W0, const float* __restrict__ W1,
                             u16* __restrict__ A0, u16* __restrict__ A1) {
  int tid = blockIdx.x * 256 + threadIdx.x;
  if (tid < 25600) {  // conv0: 50 ktiles * 8 mtiles * 64 lanes
    int lane = tid & 63;
    int kt = tid >> 9;
    int p = ((tid >> 6) & 7) * 16 + (lane & 15);
    int oc = (p & 3) * 32 + ((p >> 5) & 3) * 8 + ((p >> 4) & 1) * 4 + ((p >> 2) & 3);
    int kb = kt * 32 + (lane >> 4) * 8;
#pragma unroll
    for (int j = 0; j < 8; ++j) {
      int k = kb + j;
      int pos = k >> 6, ic = k & 63;
      int ky = pos / 5, kx = pos - ky * 5;
      A0[tid * 8 + j] = f2bf(W0[((oc * 64 + ic) * 5 + ky) * 5 + kx]);
    }
  } else if (tid < 25600 + 9216) {  // conv1: 18 ktiles * 8 * 64
    int t2 = tid - 25600;
    int lane = t2 & 63;
    int kt = t2 >> 9;
    int p = ((t2 >> 6) & 7) * 16 + (lane & 15);
    int oc = (p & 3) * 32 + ((p >> 5) & 3) * 8 + ((p >> 4) & 1) * 4 + ((p >> 2) & 3);
    int kb = kt * 32 + (lane >> 4) * 8;
#pragma unroll
    for (int j = 0; j < 8; ++j) {
      int k = kb + j;
      int pos = k >> 6, ic = k & 63;
      int ky = pos / 3, kx = pos - ky * 3;
      A1[t2 * 8 + j] = f2bf(W1[((oc * 64 + ic) * 3 + ky) * 3 + kx]);
    }
  }
}

// ---------------- A-fragment register ring, persistent across barriers ----------------
#define RD 6  // ring depth: 12 outstanding loads, 48 VGPRs, lives through phase 2
struct ARing {
  bf16x8 r0[RD], r1[RD];
};

// prime the ring for the NEXT conv call (issued in phase 2; latency hidden under att+barrier)
__device__ __forceinline__ void ring_prime(const u16* __restrict__ wsA, int wg, int lane,
                                           ARing& g) {
  const bf16x8* A = (const bf16x8*)wsA;
  const int aidx = 2 * wg * 64 + lane;
#pragma unroll
  for (int i = 0; i < RD; ++i) {
    g.r0[i] = A[aidx + i * 512];
    g.r1[i] = A[aidx + i * 512 + 64];
  }
}

// conv body: 4 waves, wave wg owns M-tiles {2wg, 2wg+1}; ring must be pre-primed.
// img: LDS padded 12x12 image, layout idx = P*64 + (ic ^ ((P&7)<<3)), bf16.
template <int KK, int NKT, int SKB>
__device__ __forceinline__ void conv_body(const u16* __restrict__ wsA, const u16* img,
                                          int wg, int lane, ARing& g, f32x4 acc[2][4]) {
  const int ic0v = (lane >> 4) << 3;
  const int pb0 = ((lane & 15) >> 3) * 12 + (lane & 7);
  const bf16x8* A = (const bf16x8*)wsA;
  const int aidx = 2 * wg * 64 + lane;
#pragma unroll
  for (int kt = 0; kt < NKT; ++kt) {
    const int slot = kt % RD;
    const bf16x8 c0 = g.r0[slot];
    const bf16x8 c1 = g.r1[slot];
    if (kt + RD < NKT) {
      g.r0[slot] = A[aidx + (kt + RD) * 512];
      g.r1[slot] = A[aidx + (kt + RD) * 512 + 64];
    }
    const int pos = kt >> 1, ih = kt & 1;
    const int ky = pos / KK, kx = pos - ky * KK;
    const int Pb = pb0 + (ky * 12 + kx + SKB);
    const int idx = Pb * 64 + ((ic0v ^ ((Pb & 7) << 3)) ^ (ih << 5));
    u16x8 b0v = *(const u16x8*)(img + idx);
    u16x8 b1v = *(const u16x8*)(img + idx + 1536);
    u16x8 b2v = *(const u16x8*)(img + idx + 3072);
    u16x8 b3v = *(const u16x8*)(img + idx + 4608);
    acc[0][0] = mfma16(c0, asbf(b0v), acc[0][0]);
    acc[1][0] = mfma16(c1, asbf(b0v), acc[1][0]);
    acc[0][1] = mfma16(c0, asbf(b1v), acc[0][1]);
    acc[1][1] = mfma16(c1, asbf(b1v), acc[1][1]);
    acc[0][2] = mfma16(c0, asbf(b2v), acc[0][2]);
    acc[1][2] = mfma16(c1, asbf(b2v), acc[1][2]);
    acc[0][3] = mfma16(c0, asbf(b3v), acc[0][3]);
    acc[1][3] = mfma16(c1, asbf(b3v), acc[1][3]);
  }
}

// ---------------- main: one batch per block; waves 0-3 = conv0 pipe (A), 4-7 = attn+conv1 (B) ----
// Software pipeline over s = 0..TT+1:
//   phase1: A: conv0(s)                  B: conv1(s-2), dots(s-1)
//   phase2: A: LSTM0(s)+prime+stage      B: LSTM1(s-2)+out+prime
//           then ALL waves: softmax + att(s-1)  (split across 512 threads)
// History rows stored PERMUTED: slot = ch*64 + l15*4 + nt  (pixel = nt*16 + l15)
__global__ void __launch_bounds__(512, 1)
convlstm_main(const float* __restrict__ x, const float* __restrict__ b0g,
              const float* __restrict__ b1g, const u16* __restrict__ wsA0,
              const u16* __restrict__ wsA1, u16* __restrict__ buf,
              float* __restrict__ out) {
  alignas(16) __shared__ u16 imgA[9216];        // conv0 input: ch0-31 = x_t, ch32-63 = h0
  alignas(16) __shared__ u16 imgB[9216];        // conv1 input: ch0-31 = att, ch32-63 = h1
  alignas(16) __shared__ u16 hist[HISTL * DD];  // h0-history rows 0..HISTL-1 (112 KB, permuted)
  alignas(16) __shared__ u16 curr[2 * DD];      // h0 row double-buffer (permuted)
  __shared__ float sdots[64];

  const int tid = threadIdx.x;
  const int b = blockIdx.x;
  const int lane = tid & 63;
  const int w = tid >> 6;
  const bool isA = (w < 4);
  const int wg = w & 3;
  const int h = lane >> 4;
  const int l15 = lane & 15;
  const int ch0 = 8 * wg + h;  // + 4*mi

  for (int i = tid; i < 9216; i += 512) {
    imgA[i] = 0;
    imgB[i] = 0;
  }

  float cst[2][4] = {};  // A: c0 state, B: c1 state
  float bi[2][4];
  {
    const float* bg = isA ? b0g : b1g;
#pragma unroll
    for (int mi = 0; mi < 2; ++mi)
#pragma unroll
      for (int j = 0; j < 4; ++j) bi[mi][j] = bg[j * 32 + ch0 + 4 * mi];
  }

  // A-side addressing
  const int Pldx = ((lane >> 3) + 2) * 12 + (lane & 7) + 2;  // x-load pixel (px = lane)
  const int swx = (Pldx & 7) << 3;
  const int Pl0 = ((l15 >> 3) + 2) * 12 + (l15 & 7) + 2;  // h-write pixel base
  const int swh = (Pl0 & 7) << 3;
  // att addressing (ALL threads): 4 slots each
  const int e4 = tid * 4;      // this thread's 4 slots of a history row
  const int chAtt = tid >> 4;  // att output channel
  const int plA = tid & 15;    // att l15 (pixel = j*16 + plA)

  __syncthreads();  // zero-init visible before x(0) staging overwrites interior

  float xr[8];  // x regs: A thread (wg,lane) owns ch = wg*8+i, px = lane
  ARing ring;   // A-waves: conv0 ring; B-waves: conv1 ring
  if (isA) {
    const float* xp0 = x + (size_t)b * DD;
    u16x8 xv;
#pragma unroll
    for (int i = 0; i < 8; ++i) xv[i] = f2bf(xp0[(wg * 8 + i) * 64 + lane]);
    *(u16x8*)&imgA[Pldx * 64 + ((wg * 8) ^ swx)] = xv;  // single 16B bandwidth-optimal write
    const float* xp1 = x + (size_t)(NB + b) * DD;
#pragma unroll
    for (int i = 0; i < 8; ++i) xr[i] = xp1[(wg * 8 + i) * 64 + lane];
    ring_prime(wsA0, wg, lane, ring);  // prime for conv0(s=0)
  }

  __syncthreads();

  for (int s = 0; s <= TT + 1; ++s) {
    f32x4 acc[2][4];
    f32x4 zz = {0.f, 0.f, 0.f, 0.f};
#pragma unroll
    for (int mi = 0; mi < 2; ++mi)
#pragma unroll
      for (int nt = 0; nt < 4; ++nt) acc[mi][nt] = zz;

    // ================= phase 1 =================
    if (isA) {
      if (s < TT) conv_body<5, 50, 0>(wsA0, imgA, wg, lane, ring, acc);
    } else {
      if (s >= 2) conv_body<3, 18, 13>(wsA1, imgB, wg, lane, ring, acc);
      const int t1 = s - 1;
      if (t1 >= 0 && t1 < TT) {  // dots(t1), rows striped over B's 4 waves
        u16x8 fv[4];
        const u16x8* rowT = (const u16x8*)&curr[(t1 & 1) * DD];
#pragma unroll
        for (int i = 0; i < 4; ++i) fv[i] = rowT[i * 64 + lane];
        int tp = wg;
        for (; tp <= t1 && tp < HISTL; tp += 4) {  // LDS rows
          const u16x8* rowP = (const u16x8*)&hist[tp * DD];
          u16x8 p0 = rowP[lane], p1 = rowP[64 + lane], p2 = rowP[128 + lane],
                p3 = rowP[192 + lane];
          float d0 = 0.f, d1 = 0.f, d2 = 0.f, d3 = 0.f;
#pragma unroll
          for (int j = 0; j < 8; ++j) {
            d0 += bf2f(fv[0][j]) * bf2f(p0[j]);
            d1 += bf2f(fv[1][j]) * bf2f(p1[j]);
            d2 += bf2f(fv[2][j]) * bf2f(p2[j]);
            d3 += bf2f(fv[3][j]) * bf2f(p3[j]);
          }
          float dsum = (d0 + d1) + (d2 + d3);
#pragma unroll
          for (int off = 32; off; off >>= 1) dsum += __shfl_xor(dsum, off, 64);
          if (lane == 0) sdots[tp] = dsum;
        }
        for (; tp < t1; tp += 4) {  // global rows HISTL..t1-1
          const u16x8* rowP = (const u16x8*)(buf + (size_t)(tp * NB + b) * DD);
          u16x8 p0 = rowP[lane], p1 = rowP[64 + lane], p2 = rowP[128 + lane],
                p3 = rowP[192 + lane];
          float d0 = 0.f, d1 = 0.f, d2 = 0.f, d3 = 0.f;
#pragma unroll
          for (int j = 0; j < 8; ++j) {
            d0 += bf2f(fv[0][j]) * bf2f(p0[j]);
            d1 += bf2f(fv[1][j]) * bf2f(p1[j]);
            d2 += bf2f(fv[2][j]) * bf2f(p2[j]);
            d3 += bf2f(fv[3][j]) * bf2f(p3[j]);
          }
          float dsum = (d0 + d1) + (d2 + d3);
#pragma unroll
          for (int off = 32; off; off >>= 1) dsum += __shfl_xor(dsum, off, 64);
          if (lane == 0) sdots[tp] = dsum;
        }
        if (tp == t1) {  // row t1 self-dot (only reached when t1 >= HISTL)
          float d0 = 0.f, d1 = 0.f, d2 = 0.f, d3 = 0.f;
#pragma unroll
          for (int j = 0; j < 8; ++j) {
            d0 += bf2f(fv[0][j]) * bf2f(fv[0][j]);
            d1 += bf2f(fv[1][j]) * bf2f(fv[1][j]);
            d2 += bf2f(fv[2][j]) * bf2f(fv[2][j]);
            d3 += bf2f(fv[3][j]) * bf2f(fv[3][j]);
          }
          float dsum = (d0 + d1) + (d2 + d3);
#pragma unroll
          for (int off = 32; off; off >>= 1) dsum += __shfl_xor(dsum, off, 64);
          if (lane == 0) sdots[t1] = dsum;
        }
      }
    }
    __syncthreads();  // ===== barrier 1: sdots + phase-1 reads done =====

    // ================= phase 2 =================
    if (isA) {
      if (s < TT) {
        u16* bufrow = buf + (size_t)(s * NB + b) * DD;
        u16* crow = &curr[(s & 1) * DD];
#pragma unroll
        for (int mi = 0; mi < 2; ++mi) {
          const int chm = ch0 + 4 * mi;
          u16x4 hv4;
#pragma unroll
          for (int nt = 0; nt < 4; ++nt) {
            float ig = acc[mi][nt][0] + bi[mi][0];
            float fg = acc[mi][nt][1] + bi[mi][1];
            float og = acc[mi][nt][2] + bi[mi][2];
            float cg = acc[mi][nt][3] + bi[mi][3];
            float cn = sigm(fg) * cst[mi][nt] + sigm(ig) * tanh_(cg);
            float hn = sigm(og) * tanh_(cn);
            cst[mi][nt] = cn;
            u16 hv = f2bf(hn);
            hv4[nt] = hv;
            imgA[(Pl0 + 24 * nt) * 64 + ((32 + chm) ^ swh)] = hv;
          }
          const int dbase = chm * 64 + l15 * 4;  // permuted row layout
          *(u16x4*)&crow[dbase] = hv4;
          if (s < HISTL)
            *(u16x4*)&hist[s * DD + dbase] = hv4;
          else
            *(u16x4*)(bufrow + dbase) = hv4;
        }
        if (s + 1 < TT)  // prime conv0(s+1) ring: latency hidden under att + barrier
          ring_prime(wsA0, wg, lane, ring);
        if (s + 1 < TT) {  // stage x(s+1) from regs, single 16B write
          u16x8 xv;
#pragma unroll
          for (int i = 0; i < 8; ++i) xv[i] = f2bf(xr[i]);
          *(u16x8*)&imgA[Pldx * 64 + ((wg * 8) ^ swx)] = xv;
        }
        if (s + 2 < TT) {  // issue x(s+2) loads
          const float* xp = x + (size_t)((s + 2) * NB + b) * DD;
#pragma unroll
          for (int i = 0; i < 8; ++i) xr[i] = xp[(wg * 8 + i) * 64 + lane];
        }
      }
    } else {
      const int t2 = s - 2;
      if (t2 >= 0) {  // LSTM1(t2) + out
        float* outrow = out + (size_t)(t2 * NB + b) * DD;
#pragma unroll
        for (int mi = 0; mi < 2; ++mi) {
          const int chm = ch0 + 4 * mi;
#pragma unroll
          for (int nt = 0; nt < 4; ++nt) {
            float ig = acc[mi][nt][0] + bi[mi][0];
            float fg = acc[mi][nt][1] + bi[mi][1];
            float og = acc[mi][nt][2] + bi[mi][2];
            float cg = acc[mi][nt][3] + bi[mi][3];
            float cn = sigm(fg) * cst[mi][nt] + sigm(ig) * tanh_(cg);
            float hn = sigm(og) * tanh_(cn);
            cst[mi][nt] = cn;
            imgB[(Pl0 + 24 * nt) * 64 + ((32 + chm) ^ swh)] = f2bf(hn);
            outrow[chm * 64 + nt * 16 + l15] = hn;
          }
        }
      }
      if (s >= 1 && s <= TT)  // prime conv1(s+1) ring (conv1 runs when s+1 >= 2)
        ring_prime(wsA1, wg, lane, ring);
    }
    {  // ---- softmax + att(t1): ALL 512 threads, 4 slots each ----
      const int t1 = s - 1;
      if (t1 >= 0 && t1 < TT) {
        float myw;  // per-wave redundant softmax; lane's weight for tp = lane
        {
          float v = (lane <= t1) ? sdots[lane] : -3.0e38f;
          float m = v;
#pragma unroll
          for (int off = 32; off; off >>= 1) m = fmaxf(m, __shfl_xor(m, off, 64));
          float e = (lane <= t1) ? __expf(v - m) : 0.f;
          float ss = e;
#pragma unroll
          for (int off = 32; off; off >>= 1) ss += __shfl_xor(ss, off, 64);
          myw = e / ss;
        }
        float av0 = 0.f, av1 = 0.f, av2 = 0.f, av3 = 0.f;
        const int lim = imin(t1, HISTL);
        int tp = 0;
        for (; tp + 1 < lim; tp += 2) {  // LDS rows, 2-way unrolled
          float wa = rdlane(myw, tp), wb = rdlane(myw, tp + 1);
          u16x4 va = *(const u16x4*)&hist[tp * DD + e4];
          u16x4 vb = *(const u16x4*)&hist[(tp + 1) * DD + e4];
          av0 = fmaf(wa, bf2f(va[0]), av0);
          av1 = fmaf(wa, bf2f(va[1]), av1);
          av2 = fmaf(wa, bf2f(va[2]), av2);
          av3 = fmaf(wa, bf2f(va[3]), av3);
          av0 = fmaf(wb, bf2f(vb[0]), av0);
          av1 = fmaf(wb, bf2f(vb[1]), av1);
          av2 = fmaf(wb, bf2f(vb[2]), av2);
          av3 = fmaf(wb, bf2f(vb[3]), av3);
        }
        if (tp < lim) {
          float wa = rdlane(myw, tp);
          u16x4 va = *(const u16x4*)&hist[tp * DD + e4];
          av0 = fmaf(wa, bf2f(va[0]), av0);
          av1 = fmaf(wa, bf2f(va[1]), av1);
          av2 = fmaf(wa, bf2f(va[2]), av2);
          av3 = fmaf(wa, bf2f(va[3]), av3);
        }
        tp = HISTL;
        for (; tp + 1 < t1; tp += 2) {  // global rows, 2-way unrolled
          float wa = rdlane(myw, tp), wb = rdlane(myw, tp + 1);
          u16x4 va = *(const u16x4*)(buf + (size_t)(tp * NB + b) * DD + e4);
          u16x4 vb = *(const u16x4*)(buf + (size_t)((tp + 1) * NB + b) * DD + e4);
          av0 = fmaf(wa, bf2f(va[0]), av0);
          av1 = fmaf(wa, bf2f(va[1]), av1);
          av2 = fmaf(wa, bf2f(va[2]), av2);
          av3 = fmaf(wa, bf2f(va[3]), av3);
          av0 = fmaf(wb, bf2f(vb[0]), av0);
          av1 = fmaf(wb, bf2f(vb[1]), av1);
          av2 = fmaf(wb, bf2f(vb[2]), av2);
          av3 = fmaf(wb, bf2f(vb[3]), av3);
        }
        if (tp < t1) {
          float wa = rdlane(myw, tp);
          u16x4 va = *(const u16x4*)(buf + (size_t)(tp * NB + b) * DD + e4);
          av0 = fmaf(wa, bf2f(va[0]), av0);
          av1 = fmaf(wa, bf2f(va[1]), av1);
          av2 = fmaf(wa, bf2f(va[2]), av2);
          av3 = fmaf(wa, bf2f(va[3]), av3);
        }
        {  // row t1 from curr
          float wt = rdlane(myw, t1);
          u16x4 v = *(const u16x4*)&curr[(t1 & 1) * DD + e4];
          av0 = fmaf(wt, bf2f(v[0]), av0);
          av1 = fmaf(wt, bf2f(v[1]), av1);
          av2 = fmaf(wt, bf2f(v[2]), av2);
          av3 = fmaf(wt, bf2f(v[3]), av3);
        }
        float av[4] = {av0, av1, av2, av3};
#pragma unroll
        for (int j = 0; j < 4; ++j) {  // un-permute: slot -> (ch, pixel) -> imgB
          const int pixel = j * 16 + plA;
          const int P = ((pixel >> 3) + 2) * 12 + (pixel & 7) + 2;
          imgB[P * 64 + (chAtt ^ ((P & 7) << 3))] = f2bf(av[j]);
        }
      }
    }
    __syncthreads();  // ===== barrier 2: imgA/imgB updates visible =====
  }
}

extern "C" void kernel_launch(void* const* d_in, const int* in_sizes, int n_in,
                              void* d_out, int out_size, void* d_ws, size_t ws_size,
                              hipStream_t stream) {
  const float* x = (const float*)d_in[0];
  const float* W0 = (const float*)d_in[1];
  const float* b0 = (const float*)d_in[2];
  const float* W1 = (const float*)d_in[3];
  const float* b1 = (const float*)d_in[4];
  float* out = (float*)d_out;

  u16* A0 = (u16*)d_ws;                        // 204800 bf16 = 400 KB
  u16* A1 = A0 + 204800;                       // 73728 bf16 = 144 KB
  u16* buf = (u16*)((char*)d_ws + (1 << 20));  // h0-history spill rows (t >= HISTL), permuted

  prep_weights<<<136, 256, 0, stream>>>(W0, W1, A0, A1);
  convlstm_main<<<256, 512, 0, stream>>>(x, b0, b1, A0, A1, buf, out);
}

// Round 12
// 1294.821 us; speedup vs baseline: 1.1754x; 1.1754x over previous
//
#include <hip/hip_runtime.h>

#define TT 40
#define NB 256
#define DD 2048
#define HISTL 28  // history rows kept in LDS; rows >= HISTL live in global ws

typedef __bf16 bf16x8 __attribute__((ext_vector_type(8)));
typedef float f32x4 __attribute__((ext_vector_type(4)));
typedef unsigned short u16;
typedef unsigned int u32;
typedef u16 u16x8 __attribute__((ext_vector_type(8)));
typedef u16 u16x4 __attribute__((ext_vector_type(4)));

__device__ __forceinline__ u16 f2bf(float f) {
  u32 u = __builtin_bit_cast(u32, f);
  return (u16)((u + 0x7fffu + ((u >> 16) & 1u)) >> 16);
}
__device__ __forceinline__ float bf2f(u16 h) {
  return __builtin_bit_cast(float, ((u32)h) << 16);
}
__device__ __forceinline__ bf16x8 asbf(u16x8 v) { return __builtin_bit_cast(bf16x8, v); }

__device__ __forceinline__ float sigm(float x) { return 1.0f / (1.0f + __expf(-x)); }
__device__ __forceinline__ float tanh_(float x) {
  float e = __expf(-2.0f * fabsf(x));
  float t = (1.0f - e) / (1.0f + e);
  return copysignf(t, x);
}

__device__ __forceinline__ f32x4 mfma16(bf16x8 a, bf16x8 b, f32x4 c) {
  return __builtin_amdgcn_mfma_f32_16x16x32_bf16(a, b, c, 0, 0, 0);
}

__device__ __forceinline__ int imin(int a, int b) { return a < b ? a : b; }

// wave-uniform lane broadcast via v_readlane (SALU path, no LDS traffic)
__device__ __forceinline__ float rdlane(float v, int l) {
  return __builtin_bit_cast(float, __builtin_amdgcn_readlane(__builtin_bit_cast(int, v), l));
}

// ---------------- weight prep: reorder W into A-fragment layout, bf16 ----------------
// A-frag for tile (kt, mt): lane l, elem j holds A[row = mt*16 + (l&15), k = kt*32 + (l>>4)*8 + j]
// row p is PERMUTED oc: oc = (p&3)*32 + ((p>>5)&3)*8 + ((p>>4)&1)*4 + ((p>>2)&3)
// K ordering: k = (ky*KK + kx)*64 + ic
__global__ void prep_weights(const float* __restrict__ W0, const float* __restrict__ W1,
                             u16* __restrict__ A0, u16* __restrict__ A1) {
  int tid = blockIdx.x * 256 + threadIdx.x;
  if (tid < 25600) {  // conv0: 50 ktiles * 8 mtiles * 64 lanes
    int lane = tid & 63;
    int kt = tid >> 9;
    int p = ((tid >> 6) & 7) * 16 + (lane & 15);
    int oc = (p & 3) * 32 + ((p >> 5) & 3) * 8 + ((p >> 4) & 1) * 4 + ((p >> 2) & 3);
    int kb = kt * 32 + (lane >> 4) * 8;
#pragma unroll
    for (int j = 0; j < 8; ++j) {
      int k = kb + j;
      int pos = k >> 6, ic = k & 63;
      int ky = pos / 5, kx = pos - ky * 5;
      A0[tid * 8 + j] = f2bf(W0[((oc * 64 + ic) * 5 + ky) * 5 + kx]);
    }
  } else if (tid < 25600 + 9216) {  // conv1: 18 ktiles * 8 * 64
    int t2 = tid - 25600;
    int lane = t2 & 63;
    int kt = t2 >> 9;
    int p = ((t2 >> 6) & 7) * 16 + (lane & 15);
    int oc = (p & 3) * 32 + ((p >> 5) & 3) * 8 + ((p >> 4) & 1) * 4 + ((p >> 2) & 3);
    int kb = kt * 32 + (lane >> 4) * 8;
#pragma unroll
    for (int j = 0; j < 8; ++j) {
      int k = kb + j;
      int pos = k >> 6, ic = k & 63;
      int ky = pos / 3, kx = pos - ky * 3;
      A1[t2 * 8 + j] = f2bf(W1[((oc * 64 + ic) * 3 + ky) * 3 + kx]);
    }
  }
}

// ---------------- conv inner loop: 4 waves, wave wg owns M-tiles {2wg, 2wg+1} ----------------
// img: LDS padded 12x12 image, layout idx = P*64 + (ic ^ ((P&7)<<3)), bf16.
// DEPTH-deep register prefetch ring (modular slots, compile-time under full unroll).
template <int KK, int NKT, int SKB, int DEPTH>
__device__ __forceinline__ void conv_loop2(const u16* __restrict__ wsA, const u16* img,
                                           int wg, int lane, f32x4 acc[2][4]) {
  const int ic0v = (lane >> 4) << 3;
  const int pb0 = ((lane & 15) >> 3) * 12 + (lane & 7);
  const bf16x8* A = (const bf16x8*)wsA;
  const int aidx = 2 * wg * 64 + lane;
  bf16x8 r0[DEPTH], r1[DEPTH];
#pragma unroll
  for (int i = 0; i < DEPTH; ++i) {
    r0[i] = A[aidx + i * 512];
    r1[i] = A[aidx + i * 512 + 64];
  }
#pragma unroll
  for (int kt = 0; kt < NKT; ++kt) {
    const int slot = kt % DEPTH;
    const bf16x8 c0 = r0[slot];
    const bf16x8 c1 = r1[slot];
    if (kt + DEPTH < NKT) {
      r0[slot] = A[aidx + (kt + DEPTH) * 512];
      r1[slot] = A[aidx + (kt + DEPTH) * 512 + 64];
    }
    const int pos = kt >> 1, ih = kt & 1;
    const int ky = pos / KK, kx = pos - ky * KK;
    const int Pb = pb0 + (ky * 12 + kx + SKB);
    const int idx = Pb * 64 + ((ic0v ^ ((Pb & 7) << 3)) ^ (ih << 5));
    u16x8 b0v = *(const u16x8*)(img + idx);
    u16x8 b1v = *(const u16x8*)(img + idx + 1536);
    u16x8 b2v = *(const u16x8*)(img + idx + 3072);
    u16x8 b3v = *(const u16x8*)(img + idx + 4608);
    acc[0][0] = mfma16(c0, asbf(b0v), acc[0][0]);
    acc[1][0] = mfma16(c1, asbf(b0v), acc[1][0]);
    acc[0][1] = mfma16(c0, asbf(b1v), acc[0][1]);
    acc[1][1] = mfma16(c1, asbf(b1v), acc[1][1]);
    acc[0][2] = mfma16(c0, asbf(b2v), acc[0][2]);
    acc[1][2] = mfma16(c1, asbf(b2v), acc[1][2]);
    acc[0][3] = mfma16(c0, asbf(b3v), acc[0][3]);
    acc[1][3] = mfma16(c1, asbf(b3v), acc[1][3]);
  }
}

// ---------------- main: one batch per block; waves 0-3 = conv0 pipe (A), 4-7 = attn+conv1 (B) ----
// Software pipeline over s = 0..TT+1:
//   phase1: A: conv0(s)                  B: conv1(s-2), dots(s-1)
//   phase2: A: LSTM0(s)+stage            B: LSTM1(s-2)+out
//           then ALL waves: softmax + att(s-1)  (split across 512 threads)
// History rows stored PERMUTED: slot = ch*64 + l15*4 + nt  (pixel = nt*16 + l15)
__global__ void __launch_bounds__(512, 1)
convlstm_main(const float* __restrict__ x, const float* __restrict__ b0g,
              const float* __restrict__ b1g, const u16* __restrict__ wsA0,
              const u16* __restrict__ wsA1, u16* __restrict__ buf,
              float* __restrict__ out) {
  alignas(16) __shared__ u16 imgA[9216];        // conv0 input: ch0-31 = x_t, ch32-63 = h0
  alignas(16) __shared__ u16 imgB[9216];        // conv1 input: ch0-31 = att, ch32-63 = h1
  alignas(16) __shared__ u16 hist[HISTL * DD];  // h0-history rows 0..HISTL-1 (112 KB, permuted)
  alignas(16) __shared__ u16 curr[2 * DD];      // h0 row double-buffer (permuted)
  __shared__ float sdots[64];

  const int tid = threadIdx.x;
  const int b = blockIdx.x;
  const int lane = tid & 63;
  const int w = tid >> 6;
  const bool isA = (w < 4);
  const int wg = w & 3;
  const int h = lane >> 4;
  const int l15 = lane & 15;
  const int ch0 = 8 * wg + h;  // + 4*mi

  for (int i = tid; i < 9216; i += 512) {
    imgA[i] = 0;
    imgB[i] = 0;
  }

  float cst[2][4] = {};  // A: c0 state, B: c1 state
  float bi[2][4];
  {
    const float* bg = isA ? b0g : b1g;
#pragma unroll
    for (int mi = 0; mi < 2; ++mi)
#pragma unroll
      for (int j = 0; j < 4; ++j) bi[mi][j] = bg[j * 32 + ch0 + 4 * mi];
  }

  // A-side addressing
  const int Pldx = ((lane >> 3) + 2) * 12 + (lane & 7) + 2;  // x-load pixel (px = lane)
  const int swx = (Pldx & 7) << 3;
  const int Pl0 = ((l15 >> 3) + 2) * 12 + (l15 & 7) + 2;  // h-write pixel base
  const int swh = (Pl0 & 7) << 3;
  // att addressing (ALL threads): 4 slots each
  const int e4 = tid * 4;      // this thread's 4 slots of a history row
  const int chAtt = tid >> 4;  // att output channel
  const int plA = tid & 15;    // att l15 (pixel = j*16 + plA)

  __syncthreads();  // zero-init visible before x(0) staging overwrites interior

  float xr[8];  // x regs: A thread (wg,lane) owns ch = wg*8+i, px = lane
  if (isA) {
    const float* xp0 = x + (size_t)b * DD;
    u16x8 xv;
#pragma unroll
    for (int i = 0; i < 8; ++i) xv[i] = f2bf(xp0[(wg * 8 + i) * 64 + lane]);
    *(u16x8*)&imgA[Pldx * 64 + ((wg * 8) ^ swx)] = xv;  // single 16B bandwidth-optimal write
    const float* xp1 = x + (size_t)(NB + b) * DD;
#pragma unroll
    for (int i = 0; i < 8; ++i) xr[i] = xp1[(wg * 8 + i) * 64 + lane];
  }

  __syncthreads();

  for (int s = 0; s <= TT + 1; ++s) {
    f32x4 acc[2][4];
    f32x4 zz = {0.f, 0.f, 0.f, 0.f};
#pragma unroll
    for (int mi = 0; mi < 2; ++mi)
#pragma unroll
      for (int nt = 0; nt < 4; ++nt) acc[mi][nt] = zz;

    // ================= phase 1 =================
    if (isA) {
      if (s < TT) conv_loop2<5, 50, 0, 8>(wsA0, imgA, wg, lane, acc);
    } else {
      if (s >= 2) conv_loop2<3, 18, 13, 6>(wsA1, imgB, wg, lane, acc);
      const int t1 = s - 1;
      if (t1 >= 0 && t1 < TT) {  // dots(t1), rows striped over B's 4 waves
        u16x8 fv[4];
        const u16x8* rowT = (const u16x8*)&curr[(t1 & 1) * DD];
#pragma unroll
        for (int i = 0; i < 4; ++i) fv[i] = rowT[i * 64 + lane];
        int tp = wg;
        for (; tp <= t1 && tp < HISTL; tp += 4) {  // LDS rows
          const u16x8* rowP = (const u16x8*)&hist[tp * DD];
          u16x8 p0 = rowP[lane], p1 = rowP[64 + lane], p2 = rowP[128 + lane],
                p3 = rowP[192 + lane];
          float d0 = 0.f, d1 = 0.f, d2 = 0.f, d3 = 0.f;
#pragma unroll
          for (int j = 0; j < 8; ++j) {
            d0 += bf2f(fv[0][j]) * bf2f(p0[j]);
            d1 += bf2f(fv[1][j]) * bf2f(p1[j]);
            d2 += bf2f(fv[2][j]) * bf2f(p2[j]);
            d3 += bf2f(fv[3][j]) * bf2f(p3[j]);
          }
          float dsum = (d0 + d1) + (d2 + d3);
#pragma unroll
          for (int off = 32; off; off >>= 1) dsum += __shfl_xor(dsum, off, 64);
          if (lane == 0) sdots[tp] = dsum;
        }
        for (; tp < t1; tp += 4) {  // global rows HISTL..t1-1
          const u16x8* rowP = (const u16x8*)(buf + (size_t)(tp * NB + b) * DD);
          u16x8 p0 = rowP[lane], p1 = rowP[64 + lane], p2 = rowP[128 + lane],
                p3 = rowP[192 + lane];
          float d0 = 0.f, d1 = 0.f, d2 = 0.f, d3 = 0.f;
#pragma unroll
          for (int j = 0; j < 8; ++j) {
            d0 += bf2f(fv[0][j]) * bf2f(p0[j]);
            d1 += bf2f(fv[1][j]) * bf2f(p1[j]);
            d2 += bf2f(fv[2][j]) * bf2f(p2[j]);
            d3 += bf2f(fv[3][j]) * bf2f(p3[j]);
          }
          float dsum = (d0 + d1) + (d2 + d3);
#pragma unroll
          for (int off = 32; off; off >>= 1) dsum += __shfl_xor(dsum, off, 64);
          if (lane == 0) sdots[tp] = dsum;
        }
        if (tp == t1) {  // row t1 self-dot (only reached when t1 >= HISTL)
          float d0 = 0.f, d1 = 0.f, d2 = 0.f, d3 = 0.f;
#pragma unroll
          for (int j = 0; j < 8; ++j) {
            d0 += bf2f(fv[0][j]) * bf2f(fv[0][j]);
            d1 += bf2f(fv[1][j]) * bf2f(fv[1][j]);
            d2 += bf2f(fv[2][j]) * bf2f(fv[2][j]);
            d3 += bf2f(fv[3][j]) * bf2f(fv[3][j]);
          }
          float dsum = (d0 + d1) + (d2 + d3);
#pragma unroll
          for (int off = 32; off; off >>= 1) dsum += __shfl_xor(dsum, off, 64);
          if (lane == 0) sdots[t1] = dsum;
        }
      }
    }
    __syncthreads();  // ===== barrier 1: sdots + row s-? stable =====

    // ================= phase 2 =================
    if (isA) {
      if (s < TT) {
        u16* bufrow = buf + (size_t)(s * NB + b) * DD;
        u16* crow = &curr[(s & 1) * DD];
#pragma unroll
        for (int mi = 0; mi < 2; ++mi) {
          const int chm = ch0 + 4 * mi;
          u16x4 hv4;
#pragma unroll
          for (int nt = 0; nt < 4; ++nt) {
            float ig = acc[mi][nt][0] + bi[mi][0];
            float fg = acc[mi][nt][1] + bi[mi][1];
            float og = acc[mi][nt][2] + bi[mi][2];
            float cg = acc[mi][nt][3] + bi[mi][3];
            float cn = sigm(fg) * cst[mi][nt] + sigm(ig) * tanh_(cg);
            float hn = sigm(og) * tanh_(cn);
            cst[mi][nt] = cn;
            u16 hv = f2bf(hn);
            hv4[nt] = hv;
            imgA[(Pl0 + 24 * nt) * 64 + ((32 + chm) ^ swh)] = hv;
          }
          const int dbase = chm * 64 + l15 * 4;  // permuted row layout
          *(u16x4*)&crow[dbase] = hv4;
          if (s < HISTL)
            *(u16x4*)&hist[s * DD + dbase] = hv4;
          else
            *(u16x4*)(bufrow + dbase) = hv4;
        }
        if (s + 1 < TT) {  // stage x(s+1) from regs, single 16B write
          u16x8 xv;
#pragma unroll
          for (int i = 0; i < 8; ++i) xv[i] = f2bf(xr[i]);
          *(u16x8*)&imgA[Pldx * 64 + ((wg * 8) ^ swx)] = xv;
        }
        if (s + 2 < TT) {  // issue x(s+2) loads
          const float* xp = x + (size_t)((s + 2) * NB + b) * DD;
#pragma unroll
          for (int i = 0; i < 8; ++i) xr[i] = xp[(wg * 8 + i) * 64 + lane];
        }
      }
    } else {
      const int t2 = s - 2;
      if (t2 >= 0) {  // LSTM1(t2) + out
        float* outrow = out + (size_t)(t2 * NB + b) * DD;
#pragma unroll
        for (int mi = 0; mi < 2; ++mi) {
          const int chm = ch0 + 4 * mi;
#pragma unroll
          for (int nt = 0; nt < 4; ++nt) {
            float ig = acc[mi][nt][0] + bi[mi][0];
            float fg = acc[mi][nt][1] + bi[mi][1];
            float og = acc[mi][nt][2] + bi[mi][2];
            float cg = acc[mi][nt][3] + bi[mi][3];
            float cn = sigm(fg) * cst[mi][nt] + sigm(ig) * tanh_(cg);
            float hn = sigm(og) * tanh_(cn);
            cst[mi][nt] = cn;
            imgB[(Pl0 + 24 * nt) * 64 + ((32 + chm) ^ swh)] = f2bf(hn);
            outrow[chm * 64 + nt * 16 + l15] = hn;
          }
        }
      }
    }
    {  // ---- softmax + att(t1): ALL 512 threads, 4 slots each ----
      const int t1 = s - 1;
      if (t1 >= 0 && t1 < TT) {
        float myw;  // per-wave redundant softmax; lane's weight for tp = lane
        {
          float v = (lane <= t1) ? sdots[lane] : -3.0e38f;
          float m = v;
#pragma unroll
          for (int off = 32; off; off >>= 1) m = fmaxf(m, __shfl_xor(m, off, 64));
          float e = (lane <= t1) ? __expf(v - m) : 0.f;
          float ss = e;
#pragma unroll
          for (int off = 32; off; off >>= 1) ss += __shfl_xor(ss, off, 64);
          myw = e / ss;
        }
        float av0 = 0.f, av1 = 0.f, av2 = 0.f, av3 = 0.f;
        const int lim = imin(t1, HISTL);
        int tp = 0;
        for (; tp + 1 < lim; tp += 2) {  // LDS rows, 2-way unrolled
          float wa = rdlane(myw, tp), wb = rdlane(myw, tp + 1);
          u16x4 va = *(const u16x4*)&hist[tp * DD + e4];
          u16x4 vb = *(const u16x4*)&hist[(tp + 1) * DD + e4];
          av0 = fmaf(wa, bf2f(va[0]), av0);
          av1 = fmaf(wa, bf2f(va[1]), av1);
          av2 = fmaf(wa, bf2f(va[2]), av2);
          av3 = fmaf(wa, bf2f(va[3]), av3);
          av0 = fmaf(wb, bf2f(vb[0]), av0);
          av1 = fmaf(wb, bf2f(vb[1]), av1);
          av2 = fmaf(wb, bf2f(vb[2]), av2);
          av3 = fmaf(wb, bf2f(vb[3]), av3);
        }
        if (tp < lim) {
          float wa = rdlane(myw, tp);
          u16x4 va = *(const u16x4*)&hist[tp * DD + e4];
          av0 = fmaf(wa, bf2f(va[0]), av0);
          av1 = fmaf(wa, bf2f(va[1]), av1);
          av2 = fmaf(wa, bf2f(va[2]), av2);
          av3 = fmaf(wa, bf2f(va[3]), av3);
        }
        tp = HISTL;
        for (; tp + 1 < t1; tp += 2) {  // global rows, 2-way unrolled
          float wa = rdlane(myw, tp), wb = rdlane(myw, tp + 1);
          u16x4 va = *(const u16x4*)(buf + (size_t)(tp * NB + b) * DD + e4);
          u16x4 vb = *(const u16x4*)(buf + (size_t)((tp + 1) * NB + b) * DD + e4);
          av0 = fmaf(wa, bf2f(va[0]), av0);
          av1 = fmaf(wa, bf2f(va[1]), av1);
          av2 = fmaf(wa, bf2f(va[2]), av2);
          av3 = fmaf(wa, bf2f(va[3]), av3);
          av0 = fmaf(wb, bf2f(vb[0]), av0);
          av1 = fmaf(wb, bf2f(vb[1]), av1);
          av2 = fmaf(wb, bf2f(vb[2]), av2);
          av3 = fmaf(wb, bf2f(vb[3]), av3);
        }
        if (tp < t1) {
          float wa = rdlane(myw, tp);
          u16x4 va = *(const u16x4*)(buf + (size_t)(tp * NB + b) * DD + e4);
          av0 = fmaf(wa, bf2f(va[0]), av0);
          av1 = fmaf(wa, bf2f(va[1]), av1);
          av2 = fmaf(wa, bf2f(va[2]), av2);
          av3 = fmaf(wa, bf2f(va[3]), av3);
        }
        {  // row t1 from curr
          float wt = rdlane(myw, t1);
          u16x4 v = *(const u16x4*)&curr[(t1 & 1) * DD + e4];
          av0 = fmaf(wt, bf2f(v[0]), av0);
          av1 = fmaf(wt, bf2f(v[1]), av1);
          av2 = fmaf(wt, bf2f(v[2]), av2);
          av3 = fmaf(wt, bf2f(v[3]), av3);
        }
        float av[4] = {av0, av1, av2, av3};
#pragma unroll
        for (int j = 0; j < 4; ++j) {  // un-permute: slot -> (ch, pixel) -> imgB
          const int pixel = j * 16 + plA;
          const int P = ((pixel >> 3) + 2) * 12 + (pixel & 7) + 2;
          imgB[P * 64 + (chAtt ^ ((P & 7) << 3))] = f2bf(av[j]);
        }
      }
    }
    __syncthreads();  // ===== barrier 2: imgA/imgB updates visible =====
  }
}

extern "C" void kernel_launch(void* const* d_in, const int* in_sizes, int n_in,
                              void* d_out, int out_size, void* d_ws, size_t ws_size,
                              hipStream_t stream) {
  const float* x = (const float*)d_in[0];
  const float* W0 = (const float*)d_in[1];
  const float* b0 = (const float*)d_in[2];
  const float* W1 = (const float*)d_in[3];
  const float* b1 = (const float*)d_in[4];
  float* out = (float*)d_out;

  u16* A0 = (u16*)d_ws;                        // 204800 bf16 = 400 KB
  u16* A1 = A0 + 204800;                       // 73728 bf16 = 144 KB
  u16* buf = (u16*)((char*)d_ws + (1 << 20));  // h0-history spill rows (t >= HISTL), permuted

  prep_weights<<<136, 256, 0, stream>>>(W0, W1, A0, A1);
  convlstm_main<<<256, 512, 0, stream>>>(x, b0, b1, A0, A1, buf, out);
}